// Round 6
// baseline (333.405 us; speedup 1.0000x reference)
//
#include <hip/hip_runtime.h>
#include <math.h>

#define HW   25600   // 160*160
#define WID  160
#define NPAR 91
#define TOPK 32
#define NCH  20      // 8-row chunks per image
#define NCAND (NCH*TOPK)   // 640 candidates per image

// workspace layout (float-element offsets into d_ws)
#define CV_OFF 0        // cand values  [16][640]
#define CI_OFF 10240    // cand indices [16][640] (int)
#define TV_OFF 20480    // top values   [16][32]
#define TI_OFF 20992    // top indices  [16][32] (int)
#define BB_OFF 21504    // bboxes [16][32][5]
#define PS_OFF 24064    // pose   [16][32][3]
#define LN_OFF 25600    // lnmks  [16][32][136]
#define CT1_OFF 95232   // int counters [16] for K_A
#define CT2_OFF 95248   // int counters [16] for K_B
// total = 95264 floats = 381056 bytes

// ---------------- K_A: peaks + chunk top-32; last chunk block does image top-32 ------
// Chunk = 8 rows (1280 px). Candidate set = peaks ∪ first-32 px of chunk: provably
// contains the chunk's true top-32 under (value desc, index asc). Rank-select gives
// unique slots. Last-arriving chunk block of each image ranks the 640 candidates.
__global__ __launch_bounds__(256) void kA_peaks(const float* __restrict__ hms,
                                                float* __restrict__ wsf,
                                                int* __restrict__ wsi)
{
  const int chunk = blockIdx.x;   // 0..19 -> rows [8c, 8c+8)
  const int b     = blockIdx.y;   // 0..15
  const int tid   = threadIdx.x;
  const float* hb = hms + (size_t)b * HW;

  __shared__ float tile[10 * 160];   // rows 8c-1 .. 8c+8
  __shared__ float cv[384];          // max independent peaks 320 + 32
  __shared__ int   ci[384];
  __shared__ int   cnt;
  __shared__ int   lastf;
  if (tid == 0) cnt = 0;

  for (int i = tid; i < 400; i += 256) {
    int r = i / 40, g = i - 40 * r;         // r 0..9, g 0..39 (float4 groups)
    int gr = chunk * 8 - 1 + r;
    float4 val;
    if (gr < 0 || gr >= 160) val = make_float4(-INFINITY, -INFINITY, -INFINITY, -INFINITY);
    else                     val = *(const float4*)(hb + gr * WID + g * 4);
    *(float4*)(tile + r * 160 + g * 4) = val;
  }
  __syncthreads();

  #pragma unroll
  for (int k = 0; k < 5; ++k) {
    int lp = tid + (k << 8);                // 0..1279 chunk-local
    int y  = lp / 160, x = lp - y * 160;    // y 0..7
    int ty = y + 1;
    float c = tile[ty * 160 + x];
    bool peak = true;
    if (x > 0) {
      if (tile[(ty - 1) * 160 + x - 1] > c) peak = false;
      if (tile[ ty      * 160 + x - 1] > c) peak = false;
      if (tile[(ty + 1) * 160 + x - 1] > c) peak = false;
    }
    if (tile[(ty - 1) * 160 + x] > c) peak = false;
    if (tile[(ty + 1) * 160 + x] > c) peak = false;
    if (x < 159) {
      if (tile[(ty - 1) * 160 + x + 1] > c) peak = false;
      if (tile[ ty      * 160 + x + 1] > c) peak = false;
      if (tile[(ty + 1) * 160 + x + 1] > c) peak = false;
    }
    if (peak || lp < 32) {
      int slot = atomicAdd(&cnt, 1);
      cv[slot] = peak ? c : 0.0f;
      ci[slot] = chunk * 1280 + lp;         // global pixel index
    }
  }
  __syncthreads();

  const int P = cnt;                        // >= 32 always
  float* outv = wsf + CV_OFF + b * NCAND + chunk * TOPK;
  int*   outi = wsi + CI_OFF + b * NCAND + chunk * TOPK;
  for (int j = tid; j < P; j += 256) {
    float vj = cv[j]; int ij = ci[j];
    int rank = 0;
    for (int m = 0; m < P; ++m) {
      float vm = cv[m]; int im = ci[m];
      rank += (vm > vj || (vm == vj && im < ij)) ? 1 : 0;
    }
    if (rank < TOPK) { outv[rank] = vj; outi[rank] = ij; }
  }

  // ---- last-block-per-image: rank the 640 candidates (former k2) ----
  __threadfence();                          // release our candidate writes
  __syncthreads();
  if (tid == 0) {
    int old = atomicAdd(wsi + CT1_OFF + b, 1);
    lastf = (old == NCH - 1);
  }
  __syncthreads();
  if (!lastf) return;
  __threadfence();                          // acquire other blocks' writes

  __shared__ float cv2[NCAND];
  __shared__ int   ci2[NCAND];
  const float* inv = wsf + CV_OFF + b * NCAND;
  const int*   ini = wsi + CI_OFF + b * NCAND;
  for (int j = tid; j < NCAND; j += 256) { cv2[j] = inv[j]; ci2[j] = ini[j]; }
  __syncthreads();
  for (int j = tid; j < NCAND; j += 256) {
    float vj = cv2[j]; int ij = ci2[j];
    int rank = 0;
    for (int m = 0; m < NCAND; ++m) {
      float vm = cv2[m]; int im = ci2[m];
      rank += (vm > vj || (vm == vj && im < ij)) ? 1 : 0;
    }
    if (rank < TOPK) {
      wsf[TV_OFF + b * TOPK + rank] = vj;
      wsi[TI_OFF + b * TOPK + rank] = ij;
    }
  }
}

// ---------------- K_B: per-detection verts/bbox/pose; last block does NMS+outputs ----
__global__ __launch_bounds__(256) void kB_tail(const float* __restrict__ pmaps,
                                               const float* __restrict__ oshapes,
                                               const float* __restrict__ pms,
                                               const float* __restrict__ ub,
                                               const float* __restrict__ sb,
                                               const float* __restrict__ eb,
                                               float* __restrict__ wsf,
                                               int* __restrict__ wsi,
                                               float* __restrict__ out)
{
  const int n   = blockIdx.x;     // 0..31 detection slot
  const int b   = blockIdx.y;     // image
  const int tid = threadIdx.x;

  __shared__ float s_sb[10200];   // 204 x 50
  __shared__ float s_eb[5916];    // 204 x 29
  __shared__ float s_ub[204];
  __shared__ float s_prm[NPAR];
  __shared__ float s_v[204];
  __shared__ float s_pyx[136];
  __shared__ int   lastf;

  {
    const float4* s4 = (const float4*)sb;
    float4* d4 = (float4*)s_sb;
    for (int i = tid; i < 2550; i += 256) d4[i] = s4[i];
    const float4* e4 = (const float4*)eb;
    float4* de = (float4*)s_eb;
    for (int i = tid; i < 1479; i += 256) de[i] = e4[i];
    if (tid < 51) ((float4*)s_ub)[tid] = ((const float4*)ub)[tid];
  }
  const int p = wsi[TI_OFF + b * TOPK + n];
  if (tid < NPAR)
    s_prm[tid] = pmaps[((size_t)b * HW + p) * NPAR + tid] * pms[NPAR + tid] + pms[tid];
  __syncthreads();

  // v[r] = ub[r] + S[r,:]·shp + E[r,:]·exp  (sequential q order == ref einsum order)
  if (tid < 204) {
    float acc = s_ub[tid];
    const float* srow = s_sb + tid * 50;
    for (int q = 0; q < 50; ++q) acc += srow[q] * s_prm[12 + q];
    const float* erow = s_eb + tid * 29;
    for (int q = 0; q < 29; ++q) acc += erow[q] * s_prm[62 + q];
    s_v[tid] = acc;
  }
  __syncthreads();

  const int ys = p / WID, xs = p - (p / WID) * WID;
  if (tid < 68) {
    float a0 = s_v[3 * tid], a1 = s_v[3 * tid + 1], a2 = s_v[3 * tid + 2];
    float s  = s_prm[0];
    float l0 = s * (a0 * s_prm[1] + a1 * s_prm[2] + a2 * s_prm[3]);
    float l1 = s * (a0 * s_prm[5] + a1 * s_prm[6] + a2 * s_prm[7]);
    float rr0 = oshapes[2 * b]     / 160.0f;
    float rr1 = oshapes[2 * b + 1] / 160.0f;
    float py = l1 + (float)ys * rr0;
    float px = l0 + (float)xs * rr1;
    float* ln = wsf + LN_OFF + ((size_t)b * TOPK + n) * 136;
    ln[2 * tid]     = py;
    ln[2 * tid + 1] = px;
    s_pyx[2 * tid]     = py;
    s_pyx[2 * tid + 1] = px;
  }
  __syncthreads();

  if (tid < 64) {
    float py = s_pyx[2 * tid], px = s_pyx[2 * tid + 1];
    float mny = py, mxy = py, mnx = px, mxx = px;
    if (tid < 4) {
      float qy = s_pyx[128 + 2 * tid], qx = s_pyx[129 + 2 * tid];
      mny = fminf(mny, qy); mxy = fmaxf(mxy, qy);
      mnx = fminf(mnx, qx); mxx = fmaxf(mxx, qx);
    }
    #pragma unroll
    for (int off = 32; off > 0; off >>= 1) {
      mny = fminf(mny, __shfl_xor(mny, off));
      mnx = fminf(mnx, __shfl_xor(mnx, off));
      mxy = fmaxf(mxy, __shfl_xor(mxy, off));
      mxx = fmaxf(mxx, __shfl_xor(mxx, off));
    }
    if (tid == 0) {
      float sc = wsf[TV_OFF + b * TOPK + n];
      bool mask = sc > 0.5f;
      float* bb = wsf + BB_OFF + ((size_t)b * TOPK + n) * 5;
      bb[0] = mask ? mny : -1.0f;
      bb[1] = mask ? mnx : -1.0f;
      bb[2] = mask ? mxy : -1.0f;
      bb[3] = mask ? mxx : -1.0f;
      bb[4] = mask ? sc  : -1.0f;
      const float R2D = 57.29577951308232f;
      float R20 = s_prm[9], R21 = s_prm[10], R22 = s_prm[11];
      float yaw = asinf(-R20) * R2D;
      float cyw = cosf(yaw);                        // degrees into cos, as the ref does
      float pitch = atan2f(R21 / cyw, R22 / cyw) * R2D;
      float roll  = atan2f(s_prm[5] / cyw, s_prm[1] / cyw) * R2D;
      float* ps = wsf + PS_OFF + ((size_t)b * TOPK + n) * 3;
      ps[0] = pitch; ps[1] = yaw; ps[2] = roll;
    }
  }

  // ---- last-block-per-image: NMS + matched + outputs (former k4) ----
  __threadfence();                          // release lnm/bbox/pose writes
  __syncthreads();
  if (tid == 0) {
    int old = atomicAdd(wsi + CT2_OFF + b, 1);
    lastf = (old == TOPK - 1);
  }
  __syncthreads();
  if (!lastf) return;
  __threadfence();                          // acquire other blocks' writes

  __shared__ float s_bbox[TOPK][5];
  __shared__ float s_topv[TOPK];
  __shared__ float s_obox[TOPK][4];
  __shared__ float s_osc[TOPK];
  __shared__ int   s_dv[TOPK];
  __shared__ int   s_match[TOPK];

  if (tid < 160) ((float*)s_bbox)[tid] = wsf[BB_OFF + b * 160 + tid];
  if (tid < TOPK) s_topv[tid] = wsf[TV_OFF + b * TOPK + tid];
  __syncthreads();

  // NMS: traversal order == identity (scores descending, masked -1 rows form suffix)
  if (tid < 64) {
    int j = tid;
    float b0 = 0.f, b1 = 0.f, b2 = 0.f, b3 = 0.f, sc = -1e30f;
    if (j < TOPK) {
      b0 = s_bbox[j][0]; b1 = s_bbox[j][1]; b2 = s_bbox[j][2]; b3 = s_bbox[j][3];
      sc = s_bbox[j][4];
    }
    float area = (b2 - b0) * (b3 - b1);
    int supp = (j >= TOPK) ? 1 : 0;
    for (int i = 0; i < TOPK; ++i) {
      float i0 = __shfl(b0, i), i1 = __shfl(b1, i);
      float i2 = __shfl(b2, i), i3 = __shfl(b3, i);
      float ia = __shfl(area, i);
      int isup = __shfl(supp, i);
      if (!isup && j > i && j < TOPK) {
        float yy1 = fmaxf(b0, i0), xx1 = fmaxf(b1, i1);
        float yy2 = fminf(b2, i2), xx2 = fminf(b3, i3);
        float inter = fmaxf(yy2 - yy1, 0.0f) * fmaxf(xx2 - xx1, 0.0f);
        float uni = area + ia - inter;
        float iou = inter / fmaxf(uni, 1e-8f);
        if (iou > 0.4f) supp = 1;
      }
    }
    bool keep = (j < TOPK) && !supp;
    unsigned long long km = __ballot(keep);
    int rank = __popcll(km & ((1ull << j) - 1ull));
    if (j < TOPK) {
      s_obox[j][0] = 0.f; s_obox[j][1] = 0.f; s_obox[j][2] = 0.f; s_obox[j][3] = 0.f;
      s_osc[j] = 0.f;
    }
    if (keep) {
      s_obox[rank][0] = b0; s_obox[rank][1] = b1;
      s_obox[rank][2] = b2; s_obox[rank][3] = b3;
      s_osc[rank] = sc;
    }
  }
  __syncthreads();

  if (tid < TOPK) {
    int dv = 1;
    #pragma unroll
    for (int c = 0; c < 4; ++c) {
      float t = s_obox[tid][c];
      if (t == -1.0f || t == 0.0f) { t = INFINITY; dv = 0; }  // -1 -> inf, 0 -> inf
      s_obox[tid][c] = t;
    }
    s_dv[tid] = dv;
  }
  __syncthreads();

  if (tid < TOPK) {
    float mysc = s_topv[tid];
    int m = 0;
    for (int sl = 0; sl < TOPK; ++sl)
      if (s_dv[sl] && s_osc[sl] == mysc) m = 1;   // literal ref 'matched' semantics
    s_match[tid] = m;
  }
  __syncthreads();

  {
    float* outb = out + (size_t)b * 192;                  // (B,32,6)
    for (int j = tid; j < 192; j += 256) {
      int sl = j / 6, c = j - 6 * sl;
      float val;
      if (c < 4)       val = s_obox[sl][c];
      else if (c == 4) val = s_osc[sl];
      else             val = 0.0f;
      outb[j] = val;
    }
    const float* lnw = wsf + LN_OFF + (size_t)b * (TOPK * 136);
    float* outl = out + 3072 + (size_t)b * 4352;          // (B,32,68,2)
    for (int j = tid; j < 4352; j += 256) {
      int nn = j / 136;
      float t = lnw[j];
      outl[j] = s_match[nn] ? ((t == -1.0f) ? INFINITY : t) : INFINITY;
    }
    const float* psw = wsf + PS_OFF + (size_t)b * (TOPK * 3);
    float* outp = out + 72704 + (size_t)b * 96;           // (B,32,3)
    for (int j = tid; j < 96; j += 256) {
      int nn = j / 3;
      float t = psw[j];
      outp[j] = s_match[nn] ? ((t == -1.0f) ? INFINITY : t) : INFINITY;
    }
  }
}

extern "C" void kernel_launch(void* const* d_in, const int* in_sizes, int n_in,
                              void* d_out, int out_size, void* d_ws, size_t ws_size,
                              hipStream_t stream) {
  const float* hms   = (const float*)d_in[0];
  const float* pmaps = (const float*)d_in[1];
  const float* osh   = (const float*)d_in[2];
  const float* pms   = (const float*)d_in[3];
  const float* ub    = (const float*)d_in[4];
  const float* sb    = (const float*)d_in[5];
  const float* eb    = (const float*)d_in[6];
  float* o   = (float*)d_out;
  float* wsf = (float*)d_ws;
  int*   wsi = (int*)d_ws;

  // zero the two 16-int completion-counter arrays (ws is poisoned 0xAA each call)
  hipMemsetAsync((char*)d_ws + CT1_OFF * 4, 0, 32 * 4, stream);

  kA_peaks<<<dim3(NCH, 16), 256, 0, stream>>>(hms, wsf, wsi);
  kB_tail <<<dim3(32, 16),  256, 0, stream>>>(pmaps, osh, pms, ub, sb, eb, wsf, wsi, o);
}

// Round 7
// 270.886 us; speedup vs baseline: 1.2308x; 1.2308x over previous
//
#include <hip/hip_runtime.h>
#include <math.h>

#define HW   25600   // 160*160
#define WID  160
#define NPAR 91
#define TOPK 32
#define NCH  20      // 8-row chunks per image
#define NCAND (NCH*TOPK)   // 640 candidates per image

// workspace layout (float-element offsets into d_ws)
#define CV_OFF 0        // cand values  [16][640]
#define CI_OFF 10240    // cand indices [16][640] (int)
#define TV_OFF 20480    // top values   [16][32]
#define BB_OFF 21504    // bboxes [16][32][5]
#define PS_OFF 24064    // pose   [16][32][3]
#define LN_OFF 25600    // lnmks  [16][32][136]
// total = 95232 floats = 380928 bytes

// ---------------- K1: LDS-tiled peak detect + exact per-chunk top-32 ----------------
// Chunk = 8 rows (1280 px). Candidate set = peaks ∪ first-32 px of chunk: provably
// contains the chunk's true top-32 under (value desc, index asc). Rank-select gives
// unique slots (distinct (v,i) pairs) -> slots 0..31 written exactly once.
__global__ __launch_bounds__(256) void k1_peaks(const float* __restrict__ hms,
                                                float* __restrict__ wsf,
                                                int* __restrict__ wsi)
{
  const int chunk = blockIdx.x;   // 0..19 -> rows [8c, 8c+8)
  const int b     = blockIdx.y;   // 0..15
  const int tid   = threadIdx.x;
  const float* hb = hms + (size_t)b * HW;

  __shared__ float tile[10 * 160];   // rows 8c-1 .. 8c+8
  __shared__ float cv[384];          // max independent peaks 320 + 32
  __shared__ int   ci[384];
  __shared__ int   cnt;
  if (tid == 0) cnt = 0;

  for (int i = tid; i < 400; i += 256) {
    int r = i / 40, g = i - 40 * r;         // r 0..9, g 0..39 (float4 groups)
    int gr = chunk * 8 - 1 + r;
    float4 val;
    if (gr < 0 || gr >= 160) val = make_float4(-INFINITY, -INFINITY, -INFINITY, -INFINITY);
    else                     val = *(const float4*)(hb + gr * WID + g * 4);
    *(float4*)(tile + r * 160 + g * 4) = val;
  }
  __syncthreads();

  #pragma unroll
  for (int k = 0; k < 5; ++k) {
    int lp = tid + (k << 8);                // 0..1279 chunk-local
    int y  = lp / 160, x = lp - y * 160;    // y 0..7
    int ty = y + 1;
    float c = tile[ty * 160 + x];
    bool peak = true;
    if (x > 0) {
      if (tile[(ty - 1) * 160 + x - 1] > c) peak = false;
      if (tile[ ty      * 160 + x - 1] > c) peak = false;
      if (tile[(ty + 1) * 160 + x - 1] > c) peak = false;
    }
    if (tile[(ty - 1) * 160 + x] > c) peak = false;
    if (tile[(ty + 1) * 160 + x] > c) peak = false;
    if (x < 159) {
      if (tile[(ty - 1) * 160 + x + 1] > c) peak = false;
      if (tile[ ty      * 160 + x + 1] > c) peak = false;
      if (tile[(ty + 1) * 160 + x + 1] > c) peak = false;
    }
    if (peak || lp < 32) {
      int slot = atomicAdd(&cnt, 1);
      cv[slot] = peak ? c : 0.0f;
      ci[slot] = chunk * 1280 + lp;         // global pixel index
    }
  }
  __syncthreads();

  const int P = cnt;                        // >= 32 always
  float* outv = wsf + CV_OFF + b * NCAND + chunk * TOPK;
  int*   outi = wsi + CI_OFF + b * NCAND + chunk * TOPK;
  for (int j = tid; j < P; j += 256) {
    float vj = cv[j]; int ij = ci[j];
    int rank = 0;
    for (int m = 0; m < P; ++m) {
      float vm = cv[m]; int im = ci[m];
      rank += (vm > vj || (vm == vj && im < ij)) ? 1 : 0;
    }
    if (rank < TOPK) { outv[rank] = vj; outi[rank] = ij; }
  }
}

// ------- K3: per-detection. Each block redundantly ranks the 640 candidates in LDS
// (no fences/atomics — k1's writes are visible across the kernel boundary), then
// computes verts/landmarks/bbox/pose for its detection, reading sb/eb rows straight
// from global (L2/L3-resident; identical q-order => bitwise-identical sums). --------
__global__ __launch_bounds__(256) void k3_verts(const float* __restrict__ pmaps,
                                                const float* __restrict__ oshapes,
                                                const float* __restrict__ pms,
                                                const float* __restrict__ ub,
                                                const float* __restrict__ sb,
                                                const float* __restrict__ eb,
                                                float* __restrict__ wsf,
                                                const int* __restrict__ wsi)
{
  const int n   = blockIdx.x;     // 0..31 detection slot
  const int b   = blockIdx.y;     // image
  const int tid = threadIdx.x;

  __shared__ float cv2[NCAND];
  __shared__ int   ci2[NCAND];
  __shared__ float s_tv[TOPK];
  __shared__ int   s_ti[TOPK];
  __shared__ float s_prm[NPAR];
  __shared__ float s_v[204];
  __shared__ float s_pyx[136];

  // exact image top-32 (recomputed per block; deterministic, identical in all blocks)
  const float* inv = wsf + CV_OFF + b * NCAND;
  const int*   ini = wsi + CI_OFF + b * NCAND;
  for (int j = tid; j < NCAND; j += 256) { cv2[j] = inv[j]; ci2[j] = ini[j]; }
  __syncthreads();
  for (int j = tid; j < NCAND; j += 256) {
    float vj = cv2[j]; int ij = ci2[j];
    int rank = 0;
    for (int m = 0; m < NCAND; ++m) {
      float vm = cv2[m]; int im = ci2[m];
      rank += (vm > vj || (vm == vj && im < ij)) ? 1 : 0;
    }
    if (rank < TOPK) {
      s_tv[rank] = vj; s_ti[rank] = ij;
      if (n == 0) wsf[TV_OFF + b * TOPK + rank] = vj;   // k4 needs scores
    }
  }
  __syncthreads();

  const int   p  = s_ti[n];
  const float sc = s_tv[n];
  if (tid < NPAR)
    s_prm[tid] = pmaps[((size_t)b * HW + p) * NPAR + tid] * pms[NPAR + tid] + pms[tid];
  __syncthreads();

  // v[r] = ub[r] + S[r,:]·shp + E[r,:]·exp  (sequential q order == ref einsum order)
  if (tid < 204) {
    float acc = ub[tid];
    const float* srow = sb + (size_t)tid * 50;
    for (int q = 0; q < 50; ++q) acc += srow[q] * s_prm[12 + q];
    const float* erow = eb + (size_t)tid * 29;
    for (int q = 0; q < 29; ++q) acc += erow[q] * s_prm[62 + q];
    s_v[tid] = acc;
  }
  __syncthreads();

  const int ys = p / WID, xs = p - (p / WID) * WID;
  if (tid < 68) {
    float a0 = s_v[3 * tid], a1 = s_v[3 * tid + 1], a2 = s_v[3 * tid + 2];
    float s  = s_prm[0];
    float l0 = s * (a0 * s_prm[1] + a1 * s_prm[2] + a2 * s_prm[3]);
    float l1 = s * (a0 * s_prm[5] + a1 * s_prm[6] + a2 * s_prm[7]);
    float rr0 = oshapes[2 * b]     / 160.0f;
    float rr1 = oshapes[2 * b + 1] / 160.0f;
    float py = l1 + (float)ys * rr0;
    float px = l0 + (float)xs * rr1;
    float* ln = wsf + LN_OFF + ((size_t)b * TOPK + n) * 136;
    ln[2 * tid]     = py;
    ln[2 * tid + 1] = px;
    s_pyx[2 * tid]     = py;
    s_pyx[2 * tid + 1] = px;
  }
  __syncthreads();

  if (tid < 64) {
    float py = s_pyx[2 * tid], px = s_pyx[2 * tid + 1];
    float mny = py, mxy = py, mnx = px, mxx = px;
    if (tid < 4) {
      float qy = s_pyx[128 + 2 * tid], qx = s_pyx[129 + 2 * tid];
      mny = fminf(mny, qy); mxy = fmaxf(mxy, qy);
      mnx = fminf(mnx, qx); mxx = fmaxf(mxx, qx);
    }
    #pragma unroll
    for (int off = 32; off > 0; off >>= 1) {
      mny = fminf(mny, __shfl_xor(mny, off));
      mnx = fminf(mnx, __shfl_xor(mnx, off));
      mxy = fmaxf(mxy, __shfl_xor(mxy, off));
      mxx = fmaxf(mxx, __shfl_xor(mxx, off));
    }
    if (tid == 0) {
      bool mask = sc > 0.5f;
      float* bb = wsf + BB_OFF + ((size_t)b * TOPK + n) * 5;
      bb[0] = mask ? mny : -1.0f;
      bb[1] = mask ? mnx : -1.0f;
      bb[2] = mask ? mxy : -1.0f;
      bb[3] = mask ? mxx : -1.0f;
      bb[4] = mask ? sc  : -1.0f;
      const float R2D = 57.29577951308232f;
      float R20 = s_prm[9], R21 = s_prm[10], R22 = s_prm[11];
      float yaw = asinf(-R20) * R2D;
      float cyw = cosf(yaw);                        // degrees into cos, as the ref does
      float pitch = atan2f(R21 / cyw, R22 / cyw) * R2D;
      float roll  = atan2f(s_prm[5] / cyw, s_prm[1] / cyw) * R2D;
      float* ps = wsf + PS_OFF + ((size_t)b * TOPK + n) * 3;
      ps[0] = pitch; ps[1] = yaw; ps[2] = roll;
    }
  }
}

// ---------------- K4: NMS + matched + output writes ----------------
__global__ __launch_bounds__(256) void k4_nms(const float* __restrict__ wsf,
                                              float* __restrict__ out)
{
  const int b   = blockIdx.x;
  const int tid = threadIdx.x;

  __shared__ float s_bbox[TOPK][5];
  __shared__ float s_topv[TOPK];
  __shared__ float s_obox[TOPK][4];
  __shared__ float s_osc[TOPK];
  __shared__ int   s_dv[TOPK];
  __shared__ int   s_match[TOPK];

  if (tid < 160) ((float*)s_bbox)[tid] = wsf[BB_OFF + b * 160 + tid];
  if (tid < TOPK) s_topv[tid] = wsf[TV_OFF + b * TOPK + tid];
  __syncthreads();

  // NMS: traversal order == identity (scores descending, masked -1 rows form suffix)
  if (tid < 64) {
    int j = tid;
    float b0 = 0.f, b1 = 0.f, b2 = 0.f, b3 = 0.f, sc = -1e30f;
    if (j < TOPK) {
      b0 = s_bbox[j][0]; b1 = s_bbox[j][1]; b2 = s_bbox[j][2]; b3 = s_bbox[j][3];
      sc = s_bbox[j][4];
    }
    float area = (b2 - b0) * (b3 - b1);
    int supp = (j >= TOPK) ? 1 : 0;
    for (int i = 0; i < TOPK; ++i) {
      float i0 = __shfl(b0, i), i1 = __shfl(b1, i);
      float i2 = __shfl(b2, i), i3 = __shfl(b3, i);
      float ia = __shfl(area, i);
      int isup = __shfl(supp, i);
      if (!isup && j > i && j < TOPK) {
        float yy1 = fmaxf(b0, i0), xx1 = fmaxf(b1, i1);
        float yy2 = fminf(b2, i2), xx2 = fminf(b3, i3);
        float inter = fmaxf(yy2 - yy1, 0.0f) * fmaxf(xx2 - xx1, 0.0f);
        float uni = area + ia - inter;
        float iou = inter / fmaxf(uni, 1e-8f);
        if (iou > 0.4f) supp = 1;
      }
    }
    bool keep = (j < TOPK) && !supp;
    unsigned long long km = __ballot(keep);
    int rank = __popcll(km & ((1ull << j) - 1ull));
    if (j < TOPK) {
      s_obox[j][0] = 0.f; s_obox[j][1] = 0.f; s_obox[j][2] = 0.f; s_obox[j][3] = 0.f;
      s_osc[j] = 0.f;
    }
    if (keep) {
      s_obox[rank][0] = b0; s_obox[rank][1] = b1;
      s_obox[rank][2] = b2; s_obox[rank][3] = b3;
      s_osc[rank] = sc;
    }
  }
  __syncthreads();

  if (tid < TOPK) {
    int dv = 1;
    #pragma unroll
    for (int c = 0; c < 4; ++c) {
      float t = s_obox[tid][c];
      if (t == -1.0f || t == 0.0f) { t = INFINITY; dv = 0; }  // -1 -> inf, 0 -> inf
      s_obox[tid][c] = t;
    }
    s_dv[tid] = dv;
  }
  __syncthreads();

  if (tid < TOPK) {
    float mysc = s_topv[tid];
    int m = 0;
    for (int sl = 0; sl < TOPK; ++sl)
      if (s_dv[sl] && s_osc[sl] == mysc) m = 1;   // literal ref 'matched' semantics
    s_match[tid] = m;
  }
  __syncthreads();

  {
    float* outb = out + (size_t)b * 192;                  // (B,32,6)
    for (int j = tid; j < 192; j += 256) {
      int sl = j / 6, c = j - 6 * sl;
      float val;
      if (c < 4)       val = s_obox[sl][c];
      else if (c == 4) val = s_osc[sl];
      else             val = 0.0f;
      outb[j] = val;
    }
    const float* lnw = wsf + LN_OFF + (size_t)b * (TOPK * 136);
    float* outl = out + 3072 + (size_t)b * 4352;          // (B,32,68,2)
    for (int j = tid; j < 4352; j += 256) {
      int n = j / 136;
      float t = lnw[j];
      outl[j] = s_match[n] ? ((t == -1.0f) ? INFINITY : t) : INFINITY;
    }
    const float* psw = wsf + PS_OFF + (size_t)b * (TOPK * 3);
    float* outp = out + 72704 + (size_t)b * 96;           // (B,32,3)
    for (int j = tid; j < 96; j += 256) {
      int n = j / 3;
      float t = psw[j];
      outp[j] = s_match[n] ? ((t == -1.0f) ? INFINITY : t) : INFINITY;
    }
  }
}

extern "C" void kernel_launch(void* const* d_in, const int* in_sizes, int n_in,
                              void* d_out, int out_size, void* d_ws, size_t ws_size,
                              hipStream_t stream) {
  const float* hms   = (const float*)d_in[0];
  const float* pmaps = (const float*)d_in[1];
  const float* osh   = (const float*)d_in[2];
  const float* pms   = (const float*)d_in[3];
  const float* ub    = (const float*)d_in[4];
  const float* sb    = (const float*)d_in[5];
  const float* eb    = (const float*)d_in[6];
  float* o   = (float*)d_out;
  float* wsf = (float*)d_ws;
  int*   wsi = (int*)d_ws;

  k1_peaks<<<dim3(NCH, 16), 256, 0, stream>>>(hms, wsf, wsi);
  k3_verts<<<dim3(32, 16), 256, 0, stream>>>(pmaps, osh, pms, ub, sb, eb, wsf, wsi);
  k4_nms  <<<16,           256, 0, stream>>>(wsf, o);
}